// Round 8
// baseline (137.099 us; speedup 1.0000x reference)
//
#include <hip/hip_runtime.h>
#include <stdint.h>

#define NSK 1000
#define TT  200
#define BB  64
#define NROW (BB * TT)      // 12800
#define SCH 20              // scan chunk (steps); 10 chunks, 1 sync each + dbuf red

__device__ __forceinline__ float frcp(float x) { return __builtin_amdgcn_rcpf(x); }
__device__ __forceinline__ float sigm(float x) { return frcp(1.f + __expf(-x)); }
__device__ __forceinline__ float tanh_fast(float x) {
  return fmaf(-2.f, frcp(1.f + __expf(2.f * x)), 1.f);   // 1 - 2/(1+e^2x)
}

typedef _Float16 half2v __attribute__((ext_vector_type(2)));
typedef _Float16 v8h __attribute__((ext_vector_type(8)));   // MFMA A/B frag (4 VGPR)
typedef float    v4f __attribute__((ext_vector_type(4)));   // MFMA C/D frag
union H2U { unsigned u; half2v h; };
union V8U { uint4 u; v8h h; };
__device__ __forceinline__ unsigned pack2h(float a, float b) {
  H2U x; x.h = (half2v){(_Float16)a, (_Float16)b}; return x.u;
}
__device__ __forceinline__ unsigned short f16bits(float x) {
  H2U u; u.h = (half2v){(_Float16)x, (_Float16)0.f}; return (unsigned short)(u.u & 0xffffu);
}
__device__ __forceinline__ float f16lo(unsigned bits) {
  H2U u; u.u = bits; return (float)u.h.x;
}
__device__ __forceinline__ float f16hi(unsigned bits) {
  H2U u; u.u = bits; return (float)u.h.y;
}
__device__ __forceinline__ v8h pk8(float4 x0, float4 x1) {
  return (v8h){(_Float16)x0.x, (_Float16)x0.y, (_Float16)x0.z, (_Float16)x0.w,
               (_Float16)x1.x, (_Float16)x1.y, (_Float16)x1.z, (_Float16)x1.w};
}

// ============ K1: fused wea + d-split scan.  512 blocks (8/batch) x 256 thr ============
// Block (b, q): owns d-columns [8q, 8q+8).  Phase 1 computes full softmax-w (all 64 m,
// 8x redundant) + e/a for its d-slice only -> LDS.  Phase 2: 4 waves x 16 m-rows scan;
// read-reduction over m completes in-block (shfl over lane-pairs + 4-wave LDS sum);
// final f16 reads -> global (complete, no partials).
__global__ __launch_bounds__(256) void wea_scan_d(
    const int* __restrict__ skills, const int* __restrict__ responses,
    const float* __restrict__ k_emb, const float* __restrict__ v_emb,
    const float* __restrict__ Mk, const float* __restrict__ eW,
    const float* __restrict__ eb, const float* __restrict__ aW,
    const float* __restrict__ ab, const float* __restrict__ Mv0,
    unsigned short* __restrict__ reads_ws)
{
  __shared__ unsigned short w_lds[TT * 68];   // 27200 B, stride 68 (8B-aligned rows)
  __shared__ unsigned ea9[TT * 9];            // 7200 B:  (e,a) pairs, block's 8 d's
  __shared__ float red[2][SCH * 33];          // 5280 B:  per-wave read partials
  // total 39680 B -> 2 blocks/CU resident (512 blocks), 8 waves/CU

  const int tid  = threadIdx.x;
  const int wv   = tid >> 6, lane = tid & 63;
  const int b    = blockIdx.x >> 3, q = blockIdx.x & 7;
  const int cq   = q >> 1, h = q & 1;         // d-slice = cols 16*cq + 8*h + [0,8)
  const int lr   = lane & 15;                 // A-row / B-col / D-col
  const int lg   = lane >> 4;                 // k-group (8 f16 each)

  // ================= Phase 1: wea for batch b (d-sliced e/a) =================
  {
    const float ebl = eb[16 * cq + lr], abl = ab[16 * cq + lr];
    #pragma unroll 1
    for (int t = wv; t < 13; t += 4) {
      const int rbase = t * 16;
      const int rl    = min(rbase + lr, TT - 1);     // clamp (tile 12 is half)
      const int row   = b * TT + rl;
      const int sk = skills[row];
      int rr = responses[row]; rr = (rr > -1) ? rr : 0;   // masked_r
      const float4* kq = (const float4*)(k_emb + (size_t)sk * 64);
      const float4* vq = (const float4*)(v_emb + (size_t)(sk + NSK * rr) * 64);
      v8h ak[2], av[2];
      #pragma unroll
      for (int u = 0; u < 2; ++u) {
        const int o = u * 8 + lg * 2;
        ak[u] = pk8(kq[o], kq[o + 1]);
        av[u] = pk8(vq[o], vq[o + 1]);
      }

      v4f acK[4], acE, acA;
      #pragma unroll
      for (int c = 0; c < 4; ++c) acK[c] = (v4f){0.f, 0.f, 0.f, 0.f};
      acE = (v4f){0.f, 0.f, 0.f, 0.f};
      acA = (v4f){0.f, 0.f, 0.f, 0.f};

      #pragma unroll
      for (int c = 0; c < 4; ++c) {                  // full w (softmax needs all m)
        const float4* mq = (const float4*)(Mk + (size_t)(16 * c + lr) * 64);
        #pragma unroll
        for (int u = 0; u < 2; ++u) {
          const int o = u * 8 + lg * 2;
          const v8h bm = pk8(mq[o], mq[o + 1]);
          acK[c] = __builtin_amdgcn_mfma_f32_16x16x32_f16(ak[u], bm, acK[c], 0, 0, 0);
        }
      }
      {                                              // e/a: only c = cq
        const float4* eq = (const float4*)(eW + (size_t)(16 * cq + lr) * 64);
        const float4* aq = (const float4*)(aW + (size_t)(16 * cq + lr) * 64);
        #pragma unroll
        for (int u = 0; u < 2; ++u) {
          const int o = u * 8 + lg * 2;
          const v8h be = pk8(eq[o], eq[o + 1]);
          const v8h ba = pk8(aq[o], aq[o + 1]);
          acE = __builtin_amdgcn_mfma_f32_16x16x32_f16(av[u], be, acE, 0, 0, 0);
          acA = __builtin_amdgcn_mfma_f32_16x16x32_f16(av[u], ba, acA, 0, 0, 0);
        }
      }

      float rs[4];
      #pragma unroll
      for (int p = 0; p < 4; ++p) {                  // softmax over 64 m per D-row
        float m = fmaxf(fmaxf(acK[0][p], acK[1][p]), fmaxf(acK[2][p], acK[3][p]));
        #pragma unroll
        for (int off = 8; off; off >>= 1) m = fmaxf(m, __shfl_xor(m, off));
        float sm = 0.f;
        #pragma unroll
        for (int c = 0; c < 4; ++c) {
          acK[c][p] = __expf(acK[c][p] - m);
          sm += acK[c][p];
        }
        #pragma unroll
        for (int off = 8; off; off >>= 1) sm += __shfl_xor(sm, off);
        rs[p] = frcp(sm);
      }

      #pragma unroll
      for (int p = 0; p < 4; ++p) {
        const int rloc = rbase + lg * 4 + p;         // D row
        if (rloc < TT) {
          #pragma unroll
          for (int c = 0; c < 4; ++c)                // full w row (64 m)
            w_lds[rloc * 68 + 16 * c + lr] = f16bits(acK[c][p] * rs[p]);
          if ((lr >> 3) == h) {                      // e/a: block's 8 d's only
            const float ev  = sigm(acE[p] + ebl);
            const float avv = tanh_fast(acA[p] + abl);
            ea9[rloc * 9 + (lr & 7)] = pack2h(ev, avv);
          }
        }
      }
    }
  }
  __syncthreads();

  // ================= Phase 2: scan; wave wv owns m in [16wv, 16wv+16) =================
  {
    const int mg = lane & 7;                  // m-pair selector: m = 16wv + 2mg + {0,1}
    const int dl = lane >> 3;                 // d_local 0..7
    const unsigned* w32 = (const unsigned*)w_lds;
    const size_t base = (size_t)b * TT;

    float Mva = Mv0[(size_t)(16 * wv + 2 * mg) * 64 + 8 * q + dl];
    float Mvb = Mv0[(size_t)(16 * wv + 2 * mg + 1) * 64 + 8 * q + dl];

    #pragma unroll 1
    for (int ch = 0; ch < TT / SCH; ++ch) {          // 10 chunks
      const int t0 = ch * SCH;
      float* rbuf = red[ch & 1];
      #pragma unroll
      for (int k = 0; k < SCH; ++k) {
        const int t = t0 + k;
        const unsigned wpair = w32[t * 34 + 8 * wv + mg];   // w[t][m], w[t][m+1]
        const unsigned eap   = ea9[t * 9 + dl];
        const float w0 = f16lo(wpair), w1 = f16hi(wpair);
        const float ev = f16lo(eap),   av = f16hi(eap);
        float rp = fmaf(w1, Mvb, w0 * Mva);            // read uses PRE-update Mv
        Mva = fmaf(w0, fmaf(-ev, Mva, av), Mva);       // Mv += w*(a - e*Mv)
        Mvb = fmaf(w1, fmaf(-ev, Mvb, av), Mvb);
        rp += __shfl_xor(rp, 1);                       // sum over mg (8 lanes)
        rp += __shfl_xor(rp, 2);
        rp += __shfl_xor(rp, 4);
        if (mg == 0) rbuf[k * 33 + wv * 8 + dl] = rp;  // wave partial (16 m)
      }
      __syncthreads();                                 // rbuf complete
      // combine 4 waves, write f16 reads: 160 vals (20 t x 8 d), 64 lanes
      for (int idx = lane + 64 * wv; idx < SCH * 8; idx += 256) {
        const int t = idx >> 3, d = idx & 7;
        const float v = (rbuf[t * 33 + d]       + rbuf[t * 33 + 8 + d])
                      + (rbuf[t * 33 + 16 + d]  + rbuf[t * 33 + 24 + d]);
        reads_ws[(base + t0 + t) * 64 + 8 * q + d] = f16bits(v);
      }
      // no trailing sync: next chunk writes red[(ch+1)&1]; its sync orders this
      // combine before red[ch&1] is reused in chunk ch+2.
    }
  }
}

// ============ K2 (MFMA, R5-verified + direct reads): 199 blocks x 256 thr ============
__global__ __launch_bounds__(256) void fp_mfma(
    const int* __restrict__ skills, const float* __restrict__ k_emb,
    const float* __restrict__ fW, const float* __restrict__ fb,
    const float* __restrict__ pW, const float* __restrict__ pb,
    const unsigned short* __restrict__ reads_ws,
    float* __restrict__ out)
{
  const int tid  = threadIdx.x;
  const int wv   = tid >> 6, lane = tid & 63;
  const int lr   = lane & 15;                        // A-row / B-col index
  const int lg   = lane >> 4;                        // k-group
  const int o0   = (blockIdx.x * 4 + wv) * 16;       // first output idx of this wave

  const unsigned idx = o0 + lr;
  const unsigned bb  = idx / 199u;
  const unsigned t2  = idx - bb * 199u;
  const int srow     = (int)(idx + bb + 1u);         // source row b*200 + t + 1

  // A fragments: t=0,1 -> reads (direct f16 load); t=2,3 -> k_emb.
  v8h ar[4];
  #pragma unroll
  for (int t = 0; t < 2; ++t) {
    V8U s;
    s.u = *(const uint4*)&reads_ws[(size_t)srow * 64 + t * 32 + lg * 8];
    ar[t] = s.h;
  }
  {
    const float4* kq = (const float4*)(k_emb + (size_t)skills[srow] * 64);
    #pragma unroll
    for (int t = 2; t < 4; ++t) {
      const int o = (t - 2) * 8 + lg * 2;
      ar[t] = pk8(kq[o], kq[o + 1]);
    }
  }

  float fbv[4], pwv[4];
  #pragma unroll
  for (int c = 0; c < 4; ++c) { fbv[c] = fb[16 * c + lr]; pwv[c] = pW[16 * c + lr]; }

  v4f acc[4];
  #pragma unroll
  for (int c = 0; c < 4; ++c) acc[c] = (v4f){0.f, 0.f, 0.f, 0.f};

  const float4* fq = (const float4*)fW;
  #pragma unroll
  for (int c = 0; c < 4; ++c) {
    const int jb = (16 * c + lr) * 32;               // float4 row base
    #pragma unroll
    for (int t = 0; t < 4; ++t) {
      const int o = jb + t * 8 + lg * 2;
      const v8h bf = pk8(fq[o], fq[o + 1]);
      acc[c] = __builtin_amdgcn_mfma_f32_16x16x32_f16(ar[t], bf, acc[c], 0, 0, 0);
    }
  }

  const float pb0 = pb[0];
  #pragma unroll
  for (int p = 0; p < 4; ++p) {
    float s = 0.f;
    #pragma unroll
    for (int c = 0; c < 4; ++c)
      s += tanh_fast(acc[c][p] + fbv[c]) * pwv[c];
    #pragma unroll
    for (int off = 8; off; off >>= 1) s += __shfl_xor(s, off);
    if (lr == lg * 4 + p)                            // this lane owns row lg*4+p
      out[(size_t)bb * (TT - 1) + t2] = sigm(s + pb0);
  }
}

extern "C" void kernel_launch(void* const* d_in, const int* in_sizes, int n_in,
                              void* d_out, int out_size, void* d_ws, size_t ws_size,
                              hipStream_t stream) {
  const int* skills    = (const int*)d_in[0];
  const int* responses = (const int*)d_in[1];
  const float* k_emb   = (const float*)d_in[2];
  const float* v_emb   = (const float*)d_in[3];
  const float* Mk      = (const float*)d_in[4];
  const float* Mv0     = (const float*)d_in[5];
  const float* fW      = (const float*)d_in[6];
  const float* fb      = (const float*)d_in[7];
  const float* eW      = (const float*)d_in[8];
  const float* eb      = (const float*)d_in[9];
  const float* aW      = (const float*)d_in[10];
  const float* ab      = (const float*)d_in[11];
  const float* pW      = (const float*)d_in[12];
  const float* pb      = (const float*)d_in[13];
  (void)in_sizes; (void)n_in; (void)out_size; (void)ws_size;

  // workspace: reads (f16, complete) = 1.6 MB only
  unsigned short* reads_ws = (unsigned short*)d_ws;

  wea_scan_d<<<dim3(BB * 8), 256, 0, stream>>>(
      skills, responses, k_emb, v_emb, Mk, eW, eb, aW, ab, Mv0, reads_ws);
  fp_mfma<<<dim3(199), 256, 0, stream>>>(
      skills, k_emb, fW, fb, pW, pb, reads_ws, (float*)d_out);
}

// Round 10
// 122.332 us; speedup vs baseline: 1.1207x; 1.1207x over previous
//
#include <hip/hip_runtime.h>
#include <stdint.h>

#define NSK 1000
#define TT  200
#define BB  64
#define NROW (BB * TT)      // 12800
#define CH  20              // scan chunk; 10 chunks, register-dbuf, no LDS
#define NSPLIT 16           // scan M-split (16 partial streams, 4 m-rows/wave)
#define PSTR ((size_t)NROW * 64)   // partial-array stride (elements)

__device__ __forceinline__ unsigned ulane_bcast(unsigned v, int l) {
  return __builtin_amdgcn_readlane(v, l);
}
__device__ __forceinline__ float frcp(float x) { return __builtin_amdgcn_rcpf(x); }
__device__ __forceinline__ float sigm(float x) { return frcp(1.f + __expf(-x)); }
__device__ __forceinline__ float tanh_fast(float x) {
  return fmaf(-2.f, frcp(1.f + __expf(2.f * x)), 1.f);   // 1 - 2/(1+e^2x)
}

typedef _Float16 half2v __attribute__((ext_vector_type(2)));
typedef _Float16 v8h __attribute__((ext_vector_type(8)));   // MFMA A/B frag (4 VGPR)
typedef float    v4f __attribute__((ext_vector_type(4)));   // MFMA C/D frag
union H2U { unsigned u; half2v h; };
union V8U { uint4 u; v8h h; };
__device__ __forceinline__ unsigned pack2h(float a, float b) {
  H2U x; x.h = (half2v){(_Float16)a, (_Float16)b}; return x.u;
}
__device__ __forceinline__ unsigned short f16bits(float x) {
  H2U u; u.h = (half2v){(_Float16)x, (_Float16)0.f}; return (unsigned short)(u.u & 0xffffu);
}
__device__ __forceinline__ float f16lo(unsigned bits) {
  H2U u; u.u = bits; return (float)u.h.x;
}
__device__ __forceinline__ float f16hi(unsigned bits) {
  H2U u; u.u = bits; return (float)u.h.y;
}
__device__ __forceinline__ v8h pk8(float4 x0, float4 x1) {
  return (v8h){(_Float16)x0.x, (_Float16)x0.y, (_Float16)x0.z, (_Float16)x0.w,
               (_Float16)x1.x, (_Float16)x1.y, (_Float16)x1.z, (_Float16)x1.w};
}

// ============ Pass A (MFMA, R4-verified): 400 blocks x 128 thr, 16 rows/wave ============
// A: row=lane&15, k=(lane>>4)*8+e.  B: col=lane&15, same k.  D: col=lane&15, row=(lane>>4)*4+reg.
__global__ __launch_bounds__(128) void wea_mfma(
    const int* __restrict__ skills, const int* __restrict__ responses,
    const float* __restrict__ k_emb, const float* __restrict__ v_emb,
    const float* __restrict__ Mk, const float* __restrict__ eW,
    const float* __restrict__ eb, const float* __restrict__ aW,
    const float* __restrict__ ab,
    unsigned* __restrict__ ea_ws, unsigned short* __restrict__ w16_ws)
{
  const int tid  = threadIdx.x;
  const int wv   = tid >> 6, lane = tid & 63;
  const int tile = blockIdx.x * 2 + wv;              // 400*2 = 800 tiles
  const int r0   = tile * 16;
  const int lr   = lane & 15;                        // A-row / B-col / D-col
  const int lg   = lane >> 4;                        // k-group (8 f16 each)

  const int sk = skills[r0 + lr];
  int rr = responses[r0 + lr]; rr = (rr > -1) ? rr : 0;   // masked_r
  const int vrow = sk + NSK * rr;

  const float4* kq = (const float4*)(k_emb + (size_t)sk * 64);
  const float4* vq = (const float4*)(v_emb + (size_t)vrow * 64);
  v8h ak[2], av[2];
  #pragma unroll
  for (int t = 0; t < 2; ++t) {
    const int o = t * 8 + lg * 2;                    // float4 index within row
    ak[t] = pk8(kq[o], kq[o + 1]);
    av[t] = pk8(vq[o], vq[o + 1]);
  }

  float ebv[4], abv[4];
  #pragma unroll
  for (int c = 0; c < 4; ++c) { ebv[c] = eb[16 * c + lr]; abv[c] = ab[16 * c + lr]; }

  v4f acK[4], acE[4], acA[4];
  #pragma unroll
  for (int c = 0; c < 4; ++c) {
    acK[c] = (v4f){0.f, 0.f, 0.f, 0.f};
    acE[c] = (v4f){0.f, 0.f, 0.f, 0.f};
    acA[c] = (v4f){0.f, 0.f, 0.f, 0.f};
  }

  #pragma unroll
  for (int c = 0; c < 4; ++c) {
    const float4* mq = (const float4*)(Mk + (size_t)(16 * c + lr) * 64);
    const float4* eq = (const float4*)(eW + (size_t)(16 * c + lr) * 64);
    const float4* aq = (const float4*)(aW + (size_t)(16 * c + lr) * 64);
    #pragma unroll
    for (int t = 0; t < 2; ++t) {
      const int o = t * 8 + lg * 2;
      const v8h bm = pk8(mq[o], mq[o + 1]);
      const v8h be = pk8(eq[o], eq[o + 1]);
      const v8h ba = pk8(aq[o], aq[o + 1]);
      acK[c] = __builtin_amdgcn_mfma_f32_16x16x32_f16(ak[t], bm, acK[c], 0, 0, 0);
      acE[c] = __builtin_amdgcn_mfma_f32_16x16x32_f16(av[t], be, acE[c], 0, 0, 0);
      acA[c] = __builtin_amdgcn_mfma_f32_16x16x32_f16(av[t], ba, acA[c], 0, 0, 0);
    }
  }

  float rs[4];
  #pragma unroll
  for (int q = 0; q < 4; ++q) {
    float m = fmaxf(fmaxf(acK[0][q], acK[1][q]), fmaxf(acK[2][q], acK[3][q]));
    #pragma unroll
    for (int off = 8; off; off >>= 1) m = fmaxf(m, __shfl_xor(m, off));
    float s = 0.f;
    #pragma unroll
    for (int c = 0; c < 4; ++c) {
      acK[c][q] = __expf(acK[c][q] - m);
      s += acK[c][q];
    }
    #pragma unroll
    for (int off = 8; off; off >>= 1) s += __shfl_xor(s, off);
    rs[q] = frcp(s);
  }

  #pragma unroll
  for (int c = 0; c < 4; ++c) {
    const int j = 16 * c + lr;
    #pragma unroll
    for (int q = 0; q < 4; ++q) {
      const int row = r0 + lg * 4 + q;
      w16_ws[(size_t)row * 64 + j] = f16bits(acK[c][q] * rs[q]);
      const float ev = sigm(acE[c][q] + ebv[c]);
      const float avv = tanh_fast(acA[c][q] + abv[c]);
      ea_ws[(size_t)row * 64 + j] = pack2h(ev, avv);
    }
  }
}

// ============ Pass B: zero-LDS scan.  256 blocks (4/batch) x 256 thr ============
// lane = d (full 64); wave owns 4 m-rows in registers (stream s16 = blk*4+wv).
// Per step: 4 readlane (VALU) + 12 FMA + 1 coalesced 128B u16 store.  No LDS,
// no syncs, no cross-lane ops.  Chunked register double-buffer for ea/w loads.
__global__ __launch_bounds__(256) void scan_nolds(
    const float* __restrict__ Mv0,
    const unsigned* __restrict__ ea_ws, const unsigned short* __restrict__ w16_ws,
    unsigned short* __restrict__ pbase)
{
  const int b    = blockIdx.x >> 2;
  const int sblk = blockIdx.x & 3;
  const int wv   = threadIdx.x >> 6;
  const int lane = threadIdx.x & 63;
  const int s16  = sblk * 4 + wv;                    // stream 0..15
  const int m0   = s16 * 4;                          // 4 m-rows of this wave
  unsigned short* ps = pbase + (size_t)s16 * PSTR;
  const size_t base = (size_t)b * TT;

  float Mv[4];
  #pragma unroll
  for (int i = 0; i < 4; ++i) Mv[i] = Mv0[(size_t)(m0 + i) * 64 + lane];

  const unsigned* eap = ea_ws + base * 64;
  const unsigned short* wp = w16_ws + base * 64;

  unsigned ea0[CH], wv0[CH], ea1[CH], wv1[CH];
  #pragma unroll
  for (int k = 0; k < CH; ++k) {                     // preload chunk 0
    ea0[k] = eap[k * 64 + lane];
    wv0[k] = (unsigned)wp[k * 64 + m0 + (lane & 3)]; // lane i<4 holds w[t][m0+i]
  }
  #pragma unroll 1
  for (int ch = 0; ch < TT / CH; ch += 2) {          // 10 chunks
    #pragma unroll
    for (int k = 0; k < CH; ++k) {                   // prefetch chunk ch+1
      ea1[k] = eap[((ch + 1) * CH + k) * 64 + lane];
      wv1[k] = (unsigned)wp[((ch + 1) * CH + k) * 64 + m0 + (lane & 3)];
    }
    #pragma unroll
    for (int k = 0; k < CH; ++k) {
      const float ev = f16lo(ea0[k]), av = f16hi(ea0[k]);
      float rp = 0.f;
      #pragma unroll
      for (int i = 0; i < 4; ++i) {
        const float wm = f16lo(ulane_bcast(wv0[k], i));
        rp = fmaf(wm, Mv[i], rp);                    // read uses PRE-update Mv
        Mv[i] = fmaf(wm, fmaf(-ev, Mv[i], av), Mv[i]);
      }
      ps[(base + ch * CH + k) * 64 + lane] = f16bits(rp);   // coalesced 128B
    }
    if ((ch + 2) * CH < TT) {
      #pragma unroll
      for (int k = 0; k < CH; ++k) {                 // prefetch chunk ch+2
        ea0[k] = eap[((ch + 2) * CH + k) * 64 + lane];
        wv0[k] = (unsigned)wp[((ch + 2) * CH + k) * 64 + m0 + (lane & 3)];
      }
    }
    #pragma unroll
    for (int k = 0; k < CH; ++k) {
      const float ev = f16lo(ea1[k]), av = f16hi(ea1[k]);
      float rp = 0.f;
      #pragma unroll
      for (int i = 0; i < 4; ++i) {
        const float wm = f16lo(ulane_bcast(wv1[k], i));
        rp = fmaf(wm, Mv[i], rp);
        Mv[i] = fmaf(wm, fmaf(-ev, Mv[i], av), Mv[i]);
      }
      ps[(base + (ch + 1) * CH + k) * 64 + lane] = f16bits(rp);
    }
  }
}

// ============ Pass C (MFMA, R7-verified, 16 partials): 199 blocks x 256 thr ============
__global__ __launch_bounds__(256) void fp_mfma(
    const int* __restrict__ skills, const float* __restrict__ k_emb,
    const float* __restrict__ fW, const float* __restrict__ fb,
    const float* __restrict__ pW, const float* __restrict__ pb,
    const unsigned short* __restrict__ pbase,
    float* __restrict__ out)
{
  const int tid  = threadIdx.x;
  const int wv   = tid >> 6, lane = tid & 63;
  const int lr   = lane & 15;                        // A-row / B-col index
  const int lg   = lane >> 4;                        // k-group
  const int o0   = (blockIdx.x * 4 + wv) * 16;       // first output idx of this wave

  const unsigned idx = o0 + lr;
  const unsigned bb  = idx / 199u;
  const unsigned t2  = idx - bb * 199u;
  const int srow     = (int)(idx + bb + 1u);         // source row b*200 + t + 1

  // A fragments: t=0,1 -> reads (pairwise tree over 16 f16 partials); t=2,3 -> k_emb.
  v8h ar[4];
  #pragma unroll
  for (int t = 0; t < 2; ++t) {
    const size_t eo = (size_t)srow * 64 + t * 32 + lg * 8;   // ushort offset
    v8h g[4];
    #pragma unroll
    for (int pp = 0; pp < 4; ++pp) {
      V8U s0, s1, s2, s3;
      s0.u = *(const uint4*)&pbase[eo + (size_t)(4 * pp) * PSTR];
      s1.u = *(const uint4*)&pbase[eo + (size_t)(4 * pp + 1) * PSTR];
      s2.u = *(const uint4*)&pbase[eo + (size_t)(4 * pp + 2) * PSTR];
      s3.u = *(const uint4*)&pbase[eo + (size_t)(4 * pp + 3) * PSTR];
      g[pp] = (s0.h + s1.h) + (s2.h + s3.h);
    }
    ar[t] = (g[0] + g[1]) + (g[2] + g[3]);
  }
  {
    const float4* kq = (const float4*)(k_emb + (size_t)skills[srow] * 64);
    #pragma unroll
    for (int t = 2; t < 4; ++t) {
      const int o = (t - 2) * 8 + lg * 2;
      ar[t] = pk8(kq[o], kq[o + 1]);
    }
  }

  float fbv[4], pwv[4];
  #pragma unroll
  for (int c = 0; c < 4; ++c) { fbv[c] = fb[16 * c + lr]; pwv[c] = pW[16 * c + lr]; }

  v4f acc[4];
  #pragma unroll
  for (int c = 0; c < 4; ++c) acc[c] = (v4f){0.f, 0.f, 0.f, 0.f};

  const float4* fq = (const float4*)fW;
  #pragma unroll
  for (int c = 0; c < 4; ++c) {
    const int jb = (16 * c + lr) * 32;               // float4 row base
    #pragma unroll
    for (int t = 0; t < 4; ++t) {
      const int o = jb + t * 8 + lg * 2;
      const v8h bf = pk8(fq[o], fq[o + 1]);
      acc[c] = __builtin_amdgcn_mfma_f32_16x16x32_f16(ar[t], bf, acc[c], 0, 0, 0);
    }
  }

  const float pb0 = pb[0];
  #pragma unroll
  for (int q = 0; q < 4; ++q) {
    float s = 0.f;
    #pragma unroll
    for (int c = 0; c < 4; ++c)
      s += tanh_fast(acc[c][q] + fbv[c]) * pwv[c];
    #pragma unroll
    for (int off = 8; off; off >>= 1) s += __shfl_xor(s, off);
    if (lr == lg * 4 + q)                            // this lane owns row lg*4+q
      out[(size_t)bb * (TT - 1) + t2] = sigm(s + pb0);
  }
}

extern "C" void kernel_launch(void* const* d_in, const int* in_sizes, int n_in,
                              void* d_out, int out_size, void* d_ws, size_t ws_size,
                              hipStream_t stream) {
  const int* skills    = (const int*)d_in[0];
  const int* responses = (const int*)d_in[1];
  const float* k_emb   = (const float*)d_in[2];
  const float* v_emb   = (const float*)d_in[3];
  const float* Mk      = (const float*)d_in[4];
  const float* Mv0     = (const float*)d_in[5];
  const float* fW      = (const float*)d_in[6];
  const float* fb      = (const float*)d_in[7];
  const float* eW      = (const float*)d_in[8];
  const float* eb      = (const float*)d_in[9];
  const float* aW      = (const float*)d_in[10];
  const float* ab      = (const float*)d_in[11];
  const float* pW      = (const float*)d_in[12];
  const float* pb      = (const float*)d_in[13];
  (void)in_sizes; (void)n_in; (void)out_size; (void)ws_size;

  // f16-packed scratch: ea (3.3MB) | w16 (1.6MB) | 16 partial arrays (1.6MB each)
  unsigned* ea_ws        = (unsigned*)d_ws;
  unsigned short* w16_ws = (unsigned short*)(ea_ws + (size_t)NROW * 64);
  unsigned short* pbase  = w16_ws + PSTR;

  wea_mfma<<<dim3(400), 128, 0, stream>>>(
      skills, responses, k_emb, v_emb, Mk, eW, eb, aW, ab, ea_ws, w16_ws);
  scan_nolds<<<dim3(BB * 4), 256, 0, stream>>>(Mv0, ea_ws, w16_ws, pbase);
  fp_mfma<<<dim3(199), 256, 0, stream>>>(
      skills, k_emb, fW, fb, pW, pb, pbase, (float*)d_out);
}